// Round 1
// baseline (2829.056 us; speedup 1.0000x reference)
//
#include <hip/hip_runtime.h>
#include <hip/hip_bf16.h>
#include <math.h>

#define N_TOK 8192
#define H_DIM 4096
#define V_DIM 32000
#define BM 128
#define BN 128
#define BK 64
#define NCT (V_DIM / BN)   /* 250 col tiles */
#define NRT (N_TOK / BM)   /* 64 row tiles  */
#define IGNORE_INDEX (-100)

typedef __attribute__((ext_vector_type(8))) short short8;
typedef __attribute__((ext_vector_type(4))) float floatx4;
typedef unsigned int u32;
typedef unsigned short u16;

#define AS1 __attribute__((address_space(1)))
#define AS3 __attribute__((address_space(3)))

__device__ __forceinline__ u16 f2bf(float f) {
    u32 u = __float_as_uint(f);
    u32 r = (u + 0x7FFFu + ((u >> 16) & 1u)) >> 16;  // round-nearest-even
    return (u16)r;
}

// fp32 -> bf16 conversion, vectorized 16B loads / 8B stores, grid-stride
__global__ void cvt_kernel(const float4* __restrict__ src, ushort4* __restrict__ dst, int n4) {
    int i = blockIdx.x * blockDim.x + threadIdx.x;
    int stride = gridDim.x * blockDim.x;
    for (; i < n4; i += stride) {
        float4 v = src[i];
        ushort4 o;
        o.x = f2bf(v.x); o.y = f2bf(v.y); o.z = f2bf(v.z); o.w = f2bf(v.w);
        dst[i] = o;
    }
}

// Fused GEMM-BT (logits tile) + per-tile online-softmax partials + target-logit capture.
// m97 structure: 128x128 tile, BK=64, 4 waves each computing 64x64 via 4x4 mfma_16x16x32_bf16.
// LDS staged via global_load_lds width=16 with XOR swizzle (j ^= row&7) to kill the
// stride-128B bank aliasing on ds_read_b128 while keeping lane-contiguous staging.
__global__ void gemm_lse_kernel(
    const u16* __restrict__ A,      // [N_TOK][H_DIM] bf16 bits
    const u16* __restrict__ W,      // [V_DIM][H_DIM] bf16 bits
    const int* __restrict__ tgt,    // [N_TOK]
    float2* __restrict__ partials,  // [NCT][N_TOK] (m, l)
    float* __restrict__ tlogit)     // [N_TOK]
{
    __shared__ __attribute__((aligned(16))) short lds_a[BM * BK];
    __shared__ __attribute__((aligned(16))) short lds_b[BN * BK];
    __shared__ float red_m[BM][2];
    __shared__ float red_l[BM][2];
    __shared__ int tgt_s[BM];

    const int bid = blockIdx.x;
    const int rowT = bid & (NRT - 1);   // row tile fast -> consecutive blocks share weight tile (L2/L3 reuse)
    const int colT = bid >> 6;
    const int row0 = rowT * BM;
    const int col0 = colT * BN;

    const int tid = threadIdx.x;
    const int lane = tid & 63;
    const int wv = tid >> 6;
    const int quad = lane >> 4;
    const int nIdx = lane & 15;
    const int rw = (wv >> 1) * 64;  // wave's row offset in tile
    const int cw = (wv & 1) * 64;   // wave's col offset in tile

    if (tid < BM) tgt_s[tid] = tgt[row0 + tid];

    floatx4 acc[4][4];
#pragma unroll
    for (int i = 0; i < 4; ++i)
#pragma unroll
        for (int j = 0; j < 4; ++j)
            acc[i][j] = (floatx4){0.f, 0.f, 0.f, 0.f};

    const u16* Ab = A + (size_t)row0 * H_DIM;
    const u16* Bb = W + (size_t)col0 * H_DIM;

    const int rsub = lane >> 3;                    // 0..7: row within 8-row chunk
    const int jsrc = (lane & 7) ^ (rsub & 7);      // swizzled k-block source

    for (int k0 = 0; k0 < H_DIM; k0 += BK) {
        __syncthreads();  // previous tile's compute done before overwrite
#pragma unroll
        for (int it = 0; it < 4; ++it) {
            int chunk = it * 4 + wv;               // 16 chunks of 8 rows = 128 rows
            int rowc = chunk * 8 + rsub;
            const u16* ga = Ab + (size_t)rowc * H_DIM + (k0 + jsrc * 8);
            __builtin_amdgcn_global_load_lds((AS1 const u32*)ga, (AS3 u32*)&lds_a[chunk * 512], 16, 0, 0);
            const u16* gb = Bb + (size_t)rowc * H_DIM + (k0 + jsrc * 8);
            __builtin_amdgcn_global_load_lds((AS1 const u32*)gb, (AS3 u32*)&lds_b[chunk * 512], 16, 0, 0);
        }
        __syncthreads();  // drains vmcnt then barrier
#pragma unroll
        for (int kk = 0; kk < 2; ++kk) {
            int sblk = kk * 4 + quad;              // k-block index within BK
            int jsw = sblk ^ (nIdx & 7);           // undo swizzle
            short8 af[4], bf[4];
#pragma unroll
            for (int i = 0; i < 4; ++i)
                af[i] = *(const short8*)&lds_a[(rw + i * 16 + nIdx) * BK + jsw * 8];
#pragma unroll
            for (int j = 0; j < 4; ++j)
                bf[j] = *(const short8*)&lds_b[(cw + j * 16 + nIdx) * BK + jsw * 8];
#pragma unroll
            for (int i = 0; i < 4; ++i)
#pragma unroll
                for (int j = 0; j < 4; ++j)
                    acc[i][j] = __builtin_amdgcn_mfma_f32_16x16x32_bf16(af[i], bf[j], acc[i][j], 0, 0, 0);
        }
    }

    // Epilogue: per-row max/sumexp over this wave's 64 cols via xor-butterfly across the
    // 16 lanes that share a row (lanes n=0..15 within each quad group), then combine the
    // two col-half waves through LDS.  C/D layout: col = lane&15, row = quad*4 + reg.
#pragma unroll
    for (int i = 0; i < 4; ++i) {
#pragma unroll
        for (int reg = 0; reg < 4; ++reg) {
            float v0 = acc[i][0][reg], v1 = acc[i][1][reg];
            float v2 = acc[i][2][reg], v3 = acc[i][3][reg];
            int rloc = rw + i * 16 + quad * 4 + reg;
            int t = tgt_s[rloc];
            int cbase = col0 + cw + nIdx;
            if (t == cbase)       tlogit[row0 + rloc] = v0;
            if (t == cbase + 16)  tlogit[row0 + rloc] = v1;
            if (t == cbase + 32)  tlogit[row0 + rloc] = v2;
            if (t == cbase + 48)  tlogit[row0 + rloc] = v3;
            float mx = fmaxf(fmaxf(v0, v1), fmaxf(v2, v3));
#pragma unroll
            for (int d = 1; d < 16; d <<= 1) mx = fmaxf(mx, __shfl_xor(mx, d, 64));
            float s = __expf(v0 - mx) + __expf(v1 - mx) + __expf(v2 - mx) + __expf(v3 - mx);
#pragma unroll
            for (int d = 1; d < 16; d <<= 1) s += __shfl_xor(s, d, 64);
            if (nIdx == 0) { red_m[rloc][wv & 1] = mx; red_l[rloc][wv & 1] = s; }
        }
    }
    __syncthreads();
    if (tid < BM) {
        float m0 = red_m[tid][0], m1 = red_m[tid][1];
        float M = fmaxf(m0, m1);
        float L = red_l[tid][0] * __expf(m0 - M) + red_l[tid][1] * __expf(m1 - M);
        partials[(size_t)colT * N_TOK + row0 + tid] = make_float2(M, L);
    }
}

// Merge 250 (m,l) partials per row -> lse; nll = lse - target_logit; reduce mean pieces.
__global__ void reduce_kernel(const float2* __restrict__ partials,
                              const float* __restrict__ tlogit,
                              const int* __restrict__ tgt,
                              float* __restrict__ accum)
{
    int row = blockIdx.x * blockDim.x + threadIdx.x;
    float nll = 0.f, cnt = 0.f;
    if (row < N_TOK) {
        float M = -INFINITY, L = 0.f;
        for (int ct = 0; ct < NCT; ++ct) {
            float2 p = partials[(size_t)ct * N_TOK + row];  // coalesced across threads
            float nm = fmaxf(M, p.x);
            L = L * __expf(M - nm) + p.y * __expf(p.x - nm);
            M = nm;
        }
        if (tgt[row] != IGNORE_INDEX) {
            nll = M + __logf(L) - tlogit[row];
            cnt = 1.f;
        }
    }
#pragma unroll
    for (int d = 32; d > 0; d >>= 1) {
        nll += __shfl_down(nll, d, 64);
        cnt += __shfl_down(cnt, d, 64);
    }
    if ((threadIdx.x & 63) == 0) {
        atomicAdd(&accum[0], nll);
        atomicAdd(&accum[1], cnt);
    }
}

__global__ void finalize_kernel(const float* __restrict__ accum, float* __restrict__ out) {
    out[0] = accum[0] / fmaxf(accum[1], 1.f);
}

extern "C" void kernel_launch(void* const* d_in, const int* in_sizes, int n_in,
                              void* d_out, int out_size, void* d_ws, size_t ws_size,
                              hipStream_t stream) {
    (void)in_sizes; (void)n_in; (void)out_size; (void)ws_size;
    const float* input = (const float*)d_in[0];   // [8192, 4096] fp32
    const float* weight = (const float*)d_in[1];  // [32000, 4096] fp32
    const int* target = (const int*)d_in[2];      // [8192] int
    float* out = (float*)d_out;                   // scalar fp32

    // workspace layout (bytes):
    //   [0,            67108864)   A bf16   (8192*4096*2)
    //   [67108864,    329252864)   W bf16   (32000*4096*2)
    //   [329252864,   345636864)   partials float2 [250][8192]
    //   [345636864,   345669632)   target logits float [8192]
    //   [345669632,   345669640)   accum {sum, count}
    char* ws = (char*)d_ws;
    u16* Abf = (u16*)ws;
    u16* Wbf = (u16*)(ws + 67108864);
    float2* partials = (float2*)(ws + 329252864);
    float* tlogit = (float*)(ws + 345636864);
    float* accum = (float*)(ws + 345669632);

    hipMemsetAsync(accum, 0, 2 * sizeof(float), stream);

    cvt_kernel<<<4096, 256, 0, stream>>>((const float4*)input, (ushort4*)Abf, N_TOK * H_DIM / 4);
    cvt_kernel<<<8192, 256, 0, stream>>>((const float4*)weight, (ushort4*)Wbf, V_DIM * H_DIM / 4);

    gemm_lse_kernel<<<NRT * NCT, 256, 0, stream>>>(Abf, Wbf, target, partials, tlogit);

    reduce_kernel<<<(N_TOK + 255) / 256, 256, 0, stream>>>(partials, tlogit, target, accum);
    finalize_kernel<<<1, 1, 0, stream>>>(accum, out);
}

// Round 2
// 2210.567 us; speedup vs baseline: 1.2798x; 1.2798x over previous
//
#include <hip/hip_runtime.h>
#include <hip/hip_bf16.h>
#include <math.h>

#define N_TOK 8192
#define H_DIM 4096
#define V_DIM 32000
#define BM 128
#define BN 128
#define BK 128                     /* K-bytes per LDS tile (fp8: 1 B/elem) */
#define NCT (V_DIM / BN)           /* 250 col tiles */
#define NRT (N_TOK / BM)           /* 64 row tiles  */
#define NCHUNK 8
#define IGNORE_INDEX (-100)

typedef __attribute__((ext_vector_type(4))) int int4v;
typedef __attribute__((ext_vector_type(8))) int int8v;
typedef __attribute__((ext_vector_type(16))) float floatx16;
typedef unsigned int u32;
typedef unsigned short u16;
typedef unsigned char u8;

#define AS1 __attribute__((address_space(1)))
#define AS3 __attribute__((address_space(3)))

// ---------- fp32 -> OCP e4m3fn conversion ----------
__device__ __forceinline__ u32 f2e4m3_manual(float x) {
    u32 u = __float_as_uint(x);
    u32 s = (u >> 24) & 0x80u;
    u32 a = u & 0x7FFFFFFFu;
    if (a >= 0x43E00000u) return s | 0x7Eu;          // >= 448 -> saturate to 448
    int e = (int)(a >> 23) - 127;
    u32 mant = a & 0x7FFFFFu;
    if (e < -9) return s;                            // below half of min subnormal
    if (e >= -6) {                                   // normal range
        u32 m = mant >> 20;
        u32 rem = mant & 0xFFFFFu;
        u32 rnd = (rem > 0x80000u) || (rem == 0x80000u && (m & 1u));
        m += rnd;
        u32 E = (u32)(e + 7);
        if (m == 8u) { m = 0u; E += 1u; }
        if (E >= 16u) return s | 0x7Eu;
        return s | (E << 3) | m;
    } else {                                         // subnormal: m * 2^-9
        int drop = 20 + (-6 - e);
        u32 full = 0x800000u | mant;
        u32 m = full >> drop;
        u32 rem = full & ((1u << drop) - 1u);
        u32 half = 1u << (drop - 1);
        u32 rnd = (rem > half) || (rem == half && (m & 1u));
        m += rnd;
        return s | m;                                // m==8 -> 0x08 == min normal, correct
    }
}

__device__ __forceinline__ u32 pk4_fp8(float a, float b, float c, float d) {
#if __has_builtin(__builtin_amdgcn_cvt_pk_fp8_f32)
    int v = __builtin_amdgcn_cvt_pk_fp8_f32(a, b, 0, false);
    v = __builtin_amdgcn_cvt_pk_fp8_f32(c, d, v, true);
    return (u32)v;
#else
    return f2e4m3_manual(a) | (f2e4m3_manual(b) << 8) |
           (f2e4m3_manual(c) << 16) | (f2e4m3_manual(d) << 24);
#endif
}

// fp32 -> fp8 with static scale; 8 elements / thread, 16B loads, 8B stores
__global__ void cvt_fp8_kernel(const float4* __restrict__ src, uint2* __restrict__ dst,
                               int n8, float scale) {
    int i = blockIdx.x * blockDim.x + threadIdx.x;
    int stride = gridDim.x * blockDim.x;
    for (; i < n8; i += stride) {
        float4 a = src[2 * i], b = src[2 * i + 1];
        uint2 o;
        o.x = pk4_fp8(a.x * scale, a.y * scale, a.z * scale, a.w * scale);
        o.y = pk4_fp8(b.x * scale, b.y * scale, b.z * scale, b.w * scale);
        dst[i] = o;
    }
}

// ---------- fused MX-fp8 GEMM-BT + online-softmax partials ----------
// 128x128 tile, BK=128 bytes, 4 waves in 2x2, each 64x64 via 2x2 of
// mfma_scale_f32_32x32x64_f8f6f4. Constant e8m0 scales: A=1.0 (0x7F),
// B=2^-6 (0x79) undoing the x64 applied during weight conversion.
// LDS rows are 128 B = 8 x 16B blocks, staged via global_load_lds(16B) with
// XOR swizzle jdst = jsrc ^ (row&7) -> ds_read_b128 conflict-free (R1: 0 conflicts).
__global__ void gemm_lse_kernel(
    const u8* __restrict__ A,       // [N_TOK][H_DIM] fp8
    const u8* __restrict__ W,       // [V_DIM][H_DIM] fp8 (x64)
    const int* __restrict__ tgt,
    float2* __restrict__ partials,  // [NCT][N_TOK] (m, l)
    float* __restrict__ tlogit)     // [N_TOK]
{
    __shared__ __attribute__((aligned(16))) u8 lds_a[BM * BK];
    __shared__ __attribute__((aligned(16))) u8 lds_b[BN * BK];
    __shared__ float red_m[BM][2];
    __shared__ float red_l[BM][2];
    __shared__ int tgt_s[BM];

    const int bid = blockIdx.x;
    const int rowT = bid / NCT;          // colT fast: consecutive blocks share A tile;
    const int colT = bid - rowT * NCT;   // fp8 W (131 MB) stays resident in L3
    const int row0 = rowT * BM;
    const int col0 = colT * BN;

    const int tid = threadIdx.x;
    const int lane = tid & 63;
    const int wv = tid >> 6;
    const int m = lane & 31;
    const int kh = lane >> 5;            // k-half within MFMA operand
    const int rw = (wv >> 1) * 64;
    const int cw = (wv & 1) * 64;

    if (tid < BM) tgt_s[tid] = tgt[row0 + tid];

    floatx16 acc[2][2];
#pragma unroll
    for (int i = 0; i < 2; ++i)
#pragma unroll
        for (int j = 0; j < 2; ++j)
#pragma unroll
            for (int r = 0; r < 16; ++r) acc[i][j][r] = 0.f;

    const u8* Ab = A + (size_t)row0 * H_DIM;
    const u8* Bb = W + (size_t)col0 * H_DIM;

    const int rsub = lane >> 3;          // 0..7 row within 8-row staging chunk
    const int jdst = lane & 7;           // dest 16B block within 128B row

    for (int k0 = 0; k0 < H_DIM; k0 += BK) {
        __syncthreads();
#pragma unroll
        for (int t = 0; t < 4; ++t) {
            int c = wv * 4 + t;                  // 16 chunks of 8 rows
            int R = c * 8 + rsub;
            int jsrc = jdst ^ (R & 7);
            const u8* ga = Ab + (size_t)R * H_DIM + (k0 + jsrc * 16);
            __builtin_amdgcn_global_load_lds((AS1 const u32*)ga, (AS3 u32*)&lds_a[c * 1024], 16, 0, 0);
            const u8* gb = Bb + (size_t)R * H_DIM + (k0 + jsrc * 16);
            __builtin_amdgcn_global_load_lds((AS1 const u32*)gb, (AS3 u32*)&lds_b[c * 1024], 16, 0, 0);
        }
        __syncthreads();
#pragma unroll
        for (int kk = 0; kk < 2; ++kk) {
            const int b0 = kk * 4 + kh * 2;      // lane's first 16B k-block
            int8v af[2], bf[2];
#pragma unroll
            for (int i = 0; i < 2; ++i) {
                const u8* base = &lds_a[(rw + i * 32 + m) * BK];
                int4v lo = *(const int4v*)(base + ((b0) ^ (m & 7)) * 16);
                int4v hi = *(const int4v*)(base + ((b0 + 1) ^ (m & 7)) * 16);
                af[i] = __builtin_shufflevector(lo, hi, 0, 1, 2, 3, 4, 5, 6, 7);
            }
#pragma unroll
            for (int j = 0; j < 2; ++j) {
                const u8* base = &lds_b[(cw + j * 32 + m) * BK];
                int4v lo = *(const int4v*)(base + ((b0) ^ (m & 7)) * 16);
                int4v hi = *(const int4v*)(base + ((b0 + 1) ^ (m & 7)) * 16);
                bf[j] = __builtin_shufflevector(lo, hi, 0, 1, 2, 3, 4, 5, 6, 7);
            }
#pragma unroll
            for (int i = 0; i < 2; ++i)
#pragma unroll
                for (int j = 0; j < 2; ++j)
                    acc[i][j] = __builtin_amdgcn_mfma_scale_f32_32x32x64_f8f6f4(
                        af[i], bf[j], acc[i][j], 0, 0,   // cbsz=fp8, blgp=fp8
                        0, 0x7F7F7F7F,                   // scale A = 1.0
                        0, 0x79797979);                  // scale B = 2^-6
        }
    }

    // Epilogue. C/D layout (32x32, shape-determined): col = lane&31,
    // row = (reg&3) + 8*(reg>>2) + 4*(lane>>5).
#pragma unroll
    for (int i = 0; i < 2; ++i) {
#pragma unroll
        for (int r = 0; r < 16; ++r) {
            float v0 = acc[i][0][r], v1 = acc[i][1][r];
            int rloc = rw + i * 32 + (r & 3) + 8 * (r >> 2) + 4 * kh;
            int t = tgt_s[rloc];
            int cbase = col0 + cw + m;
            if (t == cbase)      tlogit[row0 + rloc] = v0;
            if (t == cbase + 32) tlogit[row0 + rloc] = v1;
            float mx = fmaxf(v0, v1);
#pragma unroll
            for (int d = 1; d < 32; d <<= 1) mx = fmaxf(mx, __shfl_xor(mx, d, 64));
            float s = __expf(v0 - mx) + __expf(v1 - mx);
#pragma unroll
            for (int d = 1; d < 32; d <<= 1) s += __shfl_xor(s, d, 64);
            if (m == 0) { red_m[rloc][wv & 1] = mx; red_l[rloc][wv & 1] = s; }
        }
    }
    __syncthreads();
    if (tid < BM) {
        float m0 = red_m[tid][0], m1 = red_m[tid][1];
        float M = fmaxf(m0, m1);
        float L = red_l[tid][0] * __expf(m0 - M) + red_l[tid][1] * __expf(m1 - M);
        partials[(size_t)colT * N_TOK + row0 + tid] = make_float2(M, L);
    }
}

// ---------- two-stage partial merge ----------
__global__ void reduce1_kernel(const float2* __restrict__ partials, float2* __restrict__ part2) {
    int gid = blockIdx.x * blockDim.x + threadIdx.x;   // 0..65535
    int row = gid & (N_TOK - 1);
    int chunk = gid >> 13;                             // 0..7
    int c0 = (chunk * NCT) / NCHUNK;
    int c1 = ((chunk + 1) * NCT) / NCHUNK;
    float M = -INFINITY, L = 0.f;
    for (int ct = c0; ct < c1; ++ct) {
        float2 p = partials[(size_t)ct * N_TOK + row];
        float nm = fmaxf(M, p.x);
        L = L * __expf(M - nm) + p.y * __expf(p.x - nm);
        M = nm;
    }
    part2[gid] = make_float2(M, L);
}

__global__ void reduce2_kernel(const float2* __restrict__ part2,
                               const float* __restrict__ tlogit,
                               const int* __restrict__ tgt,
                               float* __restrict__ accum) {
    int row = blockIdx.x * blockDim.x + threadIdx.x;
    float nll = 0.f, cnt = 0.f;
    if (row < N_TOK) {
        float M = -INFINITY, L = 0.f;
#pragma unroll
        for (int c = 0; c < NCHUNK; ++c) {
            float2 p = part2[c * N_TOK + row];
            float nm = fmaxf(M, p.x);
            L = L * __expf(M - nm) + p.y * __expf(p.x - nm);
            M = nm;
        }
        if (tgt[row] != IGNORE_INDEX) {
            nll = M + __logf(L) - tlogit[row];
            cnt = 1.f;
        }
    }
#pragma unroll
    for (int d = 32; d > 0; d >>= 1) {
        nll += __shfl_down(nll, d, 64);
        cnt += __shfl_down(cnt, d, 64);
    }
    if ((threadIdx.x & 63) == 0) {
        atomicAdd(&accum[0], nll);
        atomicAdd(&accum[1], cnt);
    }
}

__global__ void finalize_kernel(const float* __restrict__ accum, float* __restrict__ out) {
    out[0] = accum[0] / fmaxf(accum[1], 1.f);
}

extern "C" void kernel_launch(void* const* d_in, const int* in_sizes, int n_in,
                              void* d_out, int out_size, void* d_ws, size_t ws_size,
                              hipStream_t stream) {
    (void)in_sizes; (void)n_in; (void)out_size; (void)ws_size;
    const float* input = (const float*)d_in[0];   // [8192, 4096] fp32
    const float* weight = (const float*)d_in[1];  // [32000, 4096] fp32
    const int* target = (const int*)d_in[2];      // [8192] int
    float* out = (float*)d_out;

    // workspace layout (bytes):
    //   [0,          33554432)   A fp8   (8192*4096)
    //   [33554432,  164626432)   W fp8   (32000*4096)
    //   [164626432, 181010432)   partials float2 [250][8192]
    //   [181010432, 181534720)   part2 float2 [8][8192]
    //   [181534720, 181567488)   tlogit float [8192]
    //   [181567488, 181567496)   accum {sum, count}
    char* ws = (char*)d_ws;
    u8* Afp8 = (u8*)ws;
    u8* Wfp8 = (u8*)(ws + 33554432);
    float2* partials = (float2*)(ws + 164626432);
    float2* part2 = (float2*)(ws + 181010432);
    float* tlogit = (float*)(ws + 181534720);
    float* accum = (float*)(ws + 181567488);

    hipMemsetAsync(accum, 0, 2 * sizeof(float), stream);

    cvt_fp8_kernel<<<4096, 256, 0, stream>>>((const float4*)input, (uint2*)Afp8,
                                             N_TOK * H_DIM / 8, 1.0f);
    cvt_fp8_kernel<<<8192, 256, 0, stream>>>((const float4*)weight, (uint2*)Wfp8,
                                             V_DIM * H_DIM / 8, 64.0f);

    gemm_lse_kernel<<<NRT * NCT, 256, 0, stream>>>(Afp8, Wfp8, target, partials, tlogit);

    reduce1_kernel<<<NCHUNK * N_TOK / 256, 256, 0, stream>>>(partials, part2);
    reduce2_kernel<<<N_TOK / 256, 256, 0, stream>>>(part2, tlogit, target, accum);
    finalize_kernel<<<1, 1, 0, stream>>>(accum, out);
}